// Round 5
// baseline (212.655 us; speedup 1.0000x reference)
//
#include <hip/hip_runtime.h>
#include <hip/hip_bf16.h>
#include <cstdint>
#include <cstddef>

#define DEVINL __device__ __forceinline__

typedef float f32x4 __attribute__((ext_vector_type(4)));
typedef float f32x16 __attribute__((ext_vector_type(16)));
typedef short s16x8 __attribute__((ext_vector_type(8)));
typedef short s16x4 __attribute__((ext_vector_type(4)));

static constexpr int Sd = 2048;   // sequence
static constexpr int Hd = 1024;   // hidden
static constexpr int NHd = 16;    // heads
static constexpr int Dd = 64;     // head dim
static constexpr int N3 = 3072;   // 3*H

DEVINL float bf2f(short u){
  unsigned int t = ((unsigned int)(unsigned short)u) << 16;
  float f; __builtin_memcpy(&f, &t, 4); return f;
}
DEVINL short f2bf(float f){
  unsigned int t; __builtin_memcpy(&t, &f, 4);
  unsigned int r = t + 0x7FFFu + ((t >> 16) & 1u);   // RNE
  return (short)(r >> 16);
}

DEVINL void gld16(const short* g, short* l){
  __builtin_amdgcn_global_load_lds((const __attribute__((address_space(1))) unsigned int*)g,
                                   (__attribute__((address_space(3))) unsigned int*)l, 16, 0, 0);
}

DEVINL int cvtpk(float lo, float hi){
  int r; asm("v_cvt_pk_bf16_f32 %0, %1, %2" : "=v"(r) : "v"(lo), "v"(hi)); return r;
}

DEVINL float fexp2(float x){
#if __has_builtin(__builtin_amdgcn_exp2f)
  return __builtin_amdgcn_exp2f(x);
#else
  return exp2f(x);
#endif
}

DEVINL f32x16 z16(){
  f32x16 v;
  #pragma unroll
  for (int i=0;i<16;i++) v[i]=0.f;
  return v;
}

// ---------------- LayerNorm + cast to bf16 ----------------
__global__ __launch_bounds__(256) void ln_kernel(const float* __restrict__ x,
                                                 const float* __restrict__ w,
                                                 const float* __restrict__ bs,
                                                 short* __restrict__ h){
  int row = blockIdx.x, tid = threadIdx.x;          // 8192 rows, 4 f32/thread
  const float* xr = x + (size_t)row * Hd;
  f32x4 v = *(const f32x4*)(xr + tid*4);
  float s1 = v[0]+v[1]+v[2]+v[3];
  float s2 = v[0]*v[0]+v[1]*v[1]+v[2]*v[2]+v[3]*v[3];
  #pragma unroll
  for (int off = 1; off < 64; off <<= 1){ s1 += __shfl_xor(s1, off); s2 += __shfl_xor(s2, off); }
  __shared__ float red[8];
  if ((tid & 63) == 0){ red[(tid>>6)*2] = s1; red[(tid>>6)*2+1] = s2; }
  __syncthreads();
  s1 = red[0]+red[2]+red[4]+red[6];
  s2 = red[1]+red[3]+red[5]+red[7];
  float mu = s1 * (1.0f/Hd);
  float rstd = rsqrtf(s2*(1.0f/Hd) - mu*mu + 1e-12f);
  f32x4 wv = *(const f32x4*)(w + tid*4);
  f32x4 bv = *(const f32x4*)(bs + tid*4);
  s16x4 o;
  #pragma unroll
  for (int i=0;i<4;i++) o[i] = f2bf((v[i]-mu)*rstd*wv[i] + bv[i]);
  *(s16x4*)(h + (size_t)row*Hd + tid*4) = o;
}

// ---------------- W cast + transpose: [K=1024][N=3072] f32 -> [N][K] bf16 ----------------
__global__ __launch_bounds__(256) void castw_kernel(const float* __restrict__ w, short* __restrict__ wT){
  __shared__ float t[32][33];
  int n0 = blockIdx.x*32, k0 = blockIdx.y*32;
  int tx = threadIdx.x, ty = threadIdx.y;           // (32,8)
  #pragma unroll
  for (int i=0;i<4;i++) t[ty + i*8][tx] = w[(size_t)(k0 + ty + i*8)*N3 + n0 + tx];
  __syncthreads();
  #pragma unroll
  for (int i=0;i<4;i++) wT[(size_t)(n0 + ty + i*8)*Hd + k0 + tx] = f2bf(t[tx][ty + i*8]);
}

// ---------------- QKV GEMM: C[8192][3072] = h @ w + b, write q/k/v bf16 head-layout ----------------
__global__ __launch_bounds__(256) void gemm_kernel(const short* __restrict__ A,
                                                   const short* __restrict__ Bt,
                                                   const float* __restrict__ bias,
                                                   short* __restrict__ qo,
                                                   short* __restrict__ ko,
                                                   short* __restrict__ vo){
  __shared__ short lA[128*32];
  __shared__ short lB[128*32];
  int bid = blockIdx.x;
  int xcd = bid & 7, idx = bid >> 3;                 // idx 0..191
  int mt = xcd*8 + (idx & 7), nt = idx >> 3;         // mt 0..63, nt 0..23
  int m0 = mt*128, n0 = nt*128;
  int tid = threadIdx.x, lane = tid & 63, wv = tid >> 6;
  int l15 = lane & 15, lq = lane >> 4;
  int wr = wv >> 1, wc = wv & 1;
  f32x4 zero = {0.f,0.f,0.f,0.f};
  f32x4 acc[4][4];
  #pragma unroll
  for (int m=0;m<4;m++)
    #pragma unroll
    for (int n=0;n<4;n++) acc[m][n] = zero;
  int flat = tid*8;
  int row0 = flat >> 5, col0 = flat & 31;
  const short* ga = A  + (size_t)(m0 + row0)*Hd + col0;
  const short* gb = Bt + (size_t)(n0 + row0)*Hd + col0;
  short* lAw = lA + wv*512;
  short* lBw = lB + wv*512;
  for (int kk = 0; kk < Hd; kk += 32){
    __syncthreads();
    gld16(ga + kk,                 lAw);
    gld16(ga + kk + (size_t)64*Hd, lAw + 2048);
    gld16(gb + kk,                 lBw);
    gld16(gb + kk + (size_t)64*Hd, lBw + 2048);
    __syncthreads();
    s16x8 af[4], bf[4];
    #pragma unroll
    for (int m=0;m<4;m++) af[m] = *(const s16x8*)(lA + (wr*64 + m*16 + l15)*32 + 8*lq);
    #pragma unroll
    for (int n=0;n<4;n++) bf[n] = *(const s16x8*)(lB + (wc*64 + n*16 + l15)*32 + 8*lq);
    #pragma unroll
    for (int m=0;m<4;m++)
      #pragma unroll
      for (int n=0;n<4;n++)
        acc[m][n] = __builtin_amdgcn_mfma_f32_16x16x32_bf16(af[m], bf[n], acc[m][n], 0, 0, 0);
  }
  #pragma unroll
  for (int n=0;n<4;n++){
    int c = n0 + wc*64 + n*16 + l15;
    float bv = bias[c];
    int part = c >> 10, hh = (c >> 6) & 15, d = c & 63;
    short* dst = part == 0 ? qo : (part == 1 ? ko : vo);
    #pragma unroll
    for (int m=0;m<4;m++){
      #pragma unroll
      for (int j=0;j<4;j++){
        int r = m0 + wr*64 + m*16 + lq*4 + j;       // global row = b*2048 + s
        int b = r >> 11, s = r & 2047;
        dst[(((size_t)((b*NHd + hh)*Sd + s)) << 6) + d] = f2bf(acc[m][n][j] + bv);
      }
    }
  }
}

// ---------------- prep: y=0 -> RoPE on K (in-place); y=1 -> V transpose ----------------
__global__ __launch_bounds__(256) void prep_kernel(short* __restrict__ k,
                                                   const short* __restrict__ v,
                                                   short* __restrict__ vT,
                                                   const float* __restrict__ sp){
  if (blockIdx.y == 0){
    unsigned int idx = blockIdx.x*256 + threadIdx.x;  // 2^19 threads over k
    unsigned int r = idx >> 2;                        // bh*2048 + s
    int quarter = idx & 3;
    int s = r & 2047;
    short* p = k + ((size_t)r << 6) + quarter*16;
    s16x8 x0 = *(s16x8*)(p), x1 = *(s16x8*)(p + 8);
    const float* sr = sp + (size_t)s*64 + quarter*8;
    f32x4 sn0 = *(const f32x4*)(sr),      sn1 = *(const f32x4*)(sr + 4);
    f32x4 cs0 = *(const f32x4*)(sr + 32), cs1 = *(const f32x4*)(sr + 36);
    s16x8 y0, y1;
    #pragma unroll
    for (int j=0;j<4;j++){
      float e = bf2f(x0[2*j]), o = bf2f(x0[2*j+1]);
      y0[2*j]   = f2bf(e*cs0[j] - o*sn0[j]);
      y0[2*j+1] = f2bf(o*cs0[j] + e*sn0[j]);
      float e1 = bf2f(x1[2*j]), o1 = bf2f(x1[2*j+1]);
      y1[2*j]   = f2bf(e1*cs1[j] - o1*sn1[j]);
      y1[2*j+1] = f2bf(o1*cs1[j] + e1*sn1[j]);
    }
    *(s16x8*)(p) = y0; *(s16x8*)(p + 8) = y1;
  } else {
    __shared__ short t[64*65];
    int s0 = (blockIdx.x & 31)*64, bh = blockIdx.x >> 5;
    int tid = threadIdx.x;
    int srow = tid >> 2, cb = (tid & 3) * 16;
    const short* src = v + (((size_t)bh*Sd + s0 + srow) << 6) + cb;
    s16x8 a = *(const s16x8*)(src), b = *(const s16x8*)(src + 8);
    #pragma unroll
    for (int j=0;j<8;j++){ t[(cb+j)*65 + srow] = a[j]; t[(cb+8+j)*65 + srow] = b[j]; }
    __syncthreads();
    int d = tid >> 2, sb = (tid & 3) * 16;
    s16x8 o0, o1;
    #pragma unroll
    for (int j=0;j<8;j++){ o0[j] = t[d*65 + sb + j]; o1[j] = t[d*65 + sb + 8 + j]; }
    size_t obase = (((size_t)bh*Dd + d) << 11) + s0 + sb;
    *(s16x8*)(vT + obase)     = o0;
    *(s16x8*)(vT + obase + 8) = o1;
  }
}

// ---------------- Flash attention: 4 waves x 32 q-rows, KV tile 64, grid 1024 ----------------
// S^T = mfma(K, Q): lane owns q = lane&31. Q-RoPE fused. K [64][64] / V^T [64][64] tiles
// staged via global_load_lds, chunk-XOR swizzle (both-sides, rule #21). 256-thr blocks ->
// 4 blocks/CU (was 2): concurrency, not per-wave work, was the R4 limiter.
__global__ __launch_bounds__(256, 5) void attn_kernel(const short* __restrict__ q,
                                                      const short* __restrict__ k,
                                                      const short* __restrict__ vT,
                                                      const float* __restrict__ sp,
                                                      float* __restrict__ out){
  __shared__ alignas(16) short kbuf[2][4096];        // [64 kv][64 d], swizzled (16 KB)
  __shared__ alignas(16) short vbuf[2][4096];        // [64 d][64 kv], swizzled (16 KB)
  int bid = blockIdx.x;
  int xcd = bid & 7, idx = bid >> 3;                 // 8 bh per XCD -> K/V L2-resident
  int bh = xcd*8 + (idx >> 4), qb = idx & 15;
  int tid = threadIdx.x, lane = tid & 63, wv = tid >> 6;
  int l31 = lane & 31, hi = lane >> 5;
  const short* kp = k  + ((size_t)bh << 17);
  const short* vp = vT + ((size_t)bh << 17);
  int qrow = qb*128 + wv*32 + l31;
  const short* qp = q + ((size_t)bh << 17) + (size_t)qrow*64;
  // ---- Q load + RoPE (lane owns row qrow; pairs adjacent within each 8-vector) ----
  const float* spq = sp + (size_t)qrow*64;
  const float qs = 0.18033688011112042f;             // 1/sqrt(64) * log2(e)
  s16x8 qf[4];                                       // B-frag: col=q(lane&31), k = d = 16*kk+8*hi+i
  #pragma unroll
  for (int kk=0;kk<4;kk++){
    s16x8 x = *(const s16x8*)(qp + kk*16 + hi*8);
    f32x4 sn = *(const f32x4*)(spq + kk*8 + hi*4);
    f32x4 cs = *(const f32x4*)(spq + 32 + kk*8 + hi*4);
    s16x8 y;
    #pragma unroll
    for (int j=0;j<4;j++){
      float e = bf2f(x[2*j]), o = bf2f(x[2*j+1]);
      y[2*j]   = f2bf((e*cs[j] - o*sn[j])*qs);
      y[2*j+1] = f2bf((o*cs[j] + e*sn[j])*qs);
    }
    qf[kk] = y;
  }
  // ---- staging: 512 chunks of 16B per tile, 2 chunks/thread (c, c+256) ----
  // chunk c: row r=c>>3, col chunk cc=c&7, source col swizzled cc^(r&7) (inverse of read XOR)
  int c1 = tid + 256;
  int koff0 = (tid >> 3)*64   + ((tid ^ (tid >> 3)) & 7)*8;
  int koff1 = (c1  >> 3)*64   + ((c1  ^ (c1  >> 3)) & 7)*8;
  int voff0 = (tid >> 3)*2048 + ((tid ^ (tid >> 3)) & 7)*8;
  int voff1 = (c1  >> 3)*2048 + ((c1  ^ (c1  >> 3)) & 7)*8;

  f32x16 ot0 = z16(), ot1 = z16();                   // O^T: col=q, row = d
  float m = -1e30f, lr = 0.f;
  int rsw = (l31 & 7);                               // read-side chunk XOR

#define STAGE(nb, t) do { \
    gld16(kp + (size_t)(t)*4096 + koff0, &kbuf[nb][0]    + wv*512); \
    gld16(kp + (size_t)(t)*4096 + koff1, &kbuf[nb][2048] + wv*512); \
    gld16(vp + (size_t)(t)*64   + voff0, &vbuf[nb][0]    + wv*512); \
    gld16(vp + (size_t)(t)*64   + voff1, &vbuf[nb][2048] + wv*512); \
  } while(0)

  STAGE(0, 0);
  __syncthreads();

  for (int t = 0; t < 32; ++t){
    int cur = t & 1;
    if (t < 31) STAGE(cur^1, t+1);                   // drained by barrier at end of t
    const short* kb = &kbuf[cur][0];
    const short* vb = &vbuf[cur][0];
    // ---- S^T = K . Q^T  (two 32x32 kv tiles, contraction d=64) ----
    f32x16 s0 = z16(), s1 = z16();
    __builtin_amdgcn_s_setprio(1);
    #pragma unroll
    for (int kk=0;kk<4;kk++){
      s16x8 kf0 = *(const s16x8*)(kb + l31*64       + (((kk*2 + hi) ^ rsw)*8));
      s0 = __builtin_amdgcn_mfma_f32_32x32x16_bf16(kf0, qf[kk], s0, 0, 0, 0);
      s16x8 kf1 = *(const s16x8*)(kb + (32+l31)*64  + (((kk*2 + hi) ^ rsw)*8));
      s1 = __builtin_amdgcn_mfma_f32_32x32x16_bf16(kf1, qf[kk], s1, 0, 0, 0);
    }
    __builtin_amdgcn_s_setprio(0);
    // ---- online softmax, lane-local per q-row (log2 domain) ----
    float tm[16];
    #pragma unroll
    for (int i=0;i<16;i++) tm[i] = fmaxf(s0[i], s1[i]);
    #pragma unroll
    for (int off=8; off>=1; off>>=1)
      #pragma unroll
      for (int i=0;i<off;i++) tm[i] = fmaxf(tm[i], tm[i+off]);
    float pmax = fmaxf(tm[0], __shfl_xor(tm[0], 32));
    if (!__all(pmax - m <= 8.0f)){                   // defer-max (T13)
      float mn = fmaxf(m, pmax);
      float al = fexp2(m - mn);
      m = mn; lr *= al;
      #pragma unroll
      for (int i=0;i<16;i++){ ot0[i] *= al; ot1[i] *= al; }
    }
    #pragma unroll
    for (int i=0;i<16;i++){ s0[i] = fexp2(s0[i]-m); s1[i] = fexp2(s1[i]-m); }
    float ra[16];
    #pragma unroll
    for (int i=0;i<16;i++) ra[i] = s0[i] + s1[i];
    #pragma unroll
    for (int off=8; off>=1; off>>=1)
      #pragma unroll
      for (int i=0;i<off;i++) ra[i] += ra[i+off];
    lr += ra[0] + __shfl_xor(ra[0], 32);
    // ---- P^T -> bf16 B-frags, O^T += V^T . P^T ----
    #pragma unroll
    for (int s4=0;s4<4;s4++){
      int base = (s4 & 1) * 8;
      int pkA0, pkA1, pkB0, pkB1;
      if (s4 < 2){
        pkA0 = cvtpk(s0[base],   s0[base+1]); pkA1 = cvtpk(s0[base+2], s0[base+3]);
        pkB0 = cvtpk(s0[base+4], s0[base+5]); pkB1 = cvtpk(s0[base+6], s0[base+7]);
      } else {
        pkA0 = cvtpk(s1[base],   s1[base+1]); pkA1 = cvtpk(s1[base+2], s1[base+3]);
        pkB0 = cvtpk(s1[base+4], s1[base+5]); pkB1 = cvtpk(s1[base+6], s1[base+7]);
      }
      int r0 = __shfl_xor(hi ? pkA0 : pkB0, 32);
      int r1 = __shfl_xor(hi ? pkA1 : pkB1, 32);
      union { int wq[4]; s16x8 v8; } u;
      u.wq[0] = hi ? r0   : pkA0;
      u.wq[1] = hi ? r1   : pkA1;
      u.wq[2] = hi ? pkB0 : r0;
      u.wq[3] = hi ? pkB1 : r1;
      __builtin_amdgcn_s_setprio(1);
      s16x8 vf0 = *(const s16x8*)(vb + l31*64      + (((s4*2 + hi) ^ rsw)*8));
      ot0 = __builtin_amdgcn_mfma_f32_32x32x16_bf16(vf0, u.v8, ot0, 0, 0, 0);
      s16x8 vf1 = *(const s16x8*)(vb + (32+l31)*64 + (((s4*2 + hi) ^ rsw)*8));
      ot1 = __builtin_amdgcn_mfma_f32_32x32x16_bf16(vf1, u.v8, ot1, 0, 0, 0);
      __builtin_amdgcn_s_setprio(0);
    }
    __syncthreads();                                 // drains vmcnt (stage) + all waves done with cur
  }
#undef STAGE
  // ---- epilogue: out[b][s=q][h*64 + d], d = 8g + 4hi + j (+32 for db=1) ----
  float inv = 1.0f / lr;
  int b = bh >> 4, hh = bh & 15;
  float* orow = out + ((size_t)(b*Sd + qrow) << 10) + hh*64;
  #pragma unroll
  for (int g=0; g<4; ++g){
    f32x4 w0, w1;
    #pragma unroll
    for (int j=0;j<4;j++){ w0[j] = ot0[4*g+j]*inv; w1[j] = ot1[4*g+j]*inv; }
    *(f32x4*)(orow + g*8 + 4*hi)      = w0;
    *(f32x4*)(orow + 32 + g*8 + 4*hi) = w1;
  }
}

extern "C" void kernel_launch(void* const* d_in, const int* in_sizes, int n_in,
                              void* d_out, int out_size, void* d_ws, size_t ws_size,
                              hipStream_t stream){
  const float* hs = (const float*)d_in[0];
  const float* sp = (const float*)d_in[1];
  const float* lw = (const float*)d_in[2];
  const float* lb = (const float*)d_in[3];
  const float* wq = (const float*)d_in[4];
  const float* bq = (const float*)d_in[5];
  float* out = (float*)d_out;
  char* ws = (char*)d_ws;
  short* h   = (short*)(ws);
  short* wT  = (short*)(ws + 16777216);
  short* vTb = (short*)(ws);                        // overlaps h: h dead after GEMM
  short* qb_ = (short*)(ws + 23068672);
  short* kb_ = (short*)(ws + 23068672 + 16777216);
  short* vb_ = (short*)(ws + 23068672 + 33554432);

  hipLaunchKernelGGL(ln_kernel,    dim3(8192),    dim3(256),   0, stream, hs, lw, lb, h);
  hipLaunchKernelGGL(castw_kernel, dim3(96,32),   dim3(32,8),  0, stream, wq, wT);
  hipLaunchKernelGGL(gemm_kernel,  dim3(1536),    dim3(256),   0, stream, h, wT, bq, qb_, kb_, vb_);
  hipLaunchKernelGGL(prep_kernel,  dim3(2048,2),  dim3(256),   0, stream, kb_, vb_, vTb, sp);
  hipLaunchKernelGGL(attn_kernel,  dim3(1024),    dim3(256),   0, stream, qb_, kb_, vTb, sp, out);
}

// Round 6
// 188.410 us; speedup vs baseline: 1.1287x; 1.1287x over previous
//
#include <hip/hip_runtime.h>
#include <hip/hip_bf16.h>
#include <cstdint>
#include <cstddef>

#define DEVINL __device__ __forceinline__

typedef float f32x4 __attribute__((ext_vector_type(4)));
typedef float f32x16 __attribute__((ext_vector_type(16)));
typedef short s16x8 __attribute__((ext_vector_type(8)));
typedef short s16x4 __attribute__((ext_vector_type(4)));

static constexpr int Sd = 2048;   // sequence
static constexpr int Hd = 1024;   // hidden
static constexpr int NHd = 16;    // heads
static constexpr int Dd = 64;     // head dim
static constexpr int N3 = 3072;   // 3*H

DEVINL float bf2f(short u){
  unsigned int t = ((unsigned int)(unsigned short)u) << 16;
  float f; __builtin_memcpy(&f, &t, 4); return f;
}
DEVINL short f2bf(float f){
  unsigned int t; __builtin_memcpy(&t, &f, 4);
  unsigned int r = t + 0x7FFFu + ((t >> 16) & 1u);   // RNE
  return (short)(r >> 16);
}

DEVINL void gld16(const short* g, short* l){
  __builtin_amdgcn_global_load_lds((const __attribute__((address_space(1))) unsigned int*)g,
                                   (__attribute__((address_space(3))) unsigned int*)l, 16, 0, 0);
}

DEVINL int cvtpk(float lo, float hi){
  int r; asm("v_cvt_pk_bf16_f32 %0, %1, %2" : "=v"(r) : "v"(lo), "v"(hi)); return r;
}

DEVINL float fexp2(float x){
#if __has_builtin(__builtin_amdgcn_exp2f)
  return __builtin_amdgcn_exp2f(x);
#else
  return exp2f(x);
#endif
}

DEVINL f32x16 z16(){
  f32x16 v;
  #pragma unroll
  for (int i=0;i<16;i++) v[i]=0.f;
  return v;
}

// ---------------- LayerNorm + cast to bf16 ----------------
__global__ __launch_bounds__(256) void ln_kernel(const float* __restrict__ x,
                                                 const float* __restrict__ w,
                                                 const float* __restrict__ bs,
                                                 short* __restrict__ h){
  int row = blockIdx.x, tid = threadIdx.x;          // 8192 rows, 4 f32/thread
  const float* xr = x + (size_t)row * Hd;
  f32x4 v = *(const f32x4*)(xr + tid*4);
  float s1 = v[0]+v[1]+v[2]+v[3];
  float s2 = v[0]*v[0]+v[1]*v[1]+v[2]*v[2]+v[3]*v[3];
  #pragma unroll
  for (int off = 1; off < 64; off <<= 1){ s1 += __shfl_xor(s1, off); s2 += __shfl_xor(s2, off); }
  __shared__ float red[8];
  if ((tid & 63) == 0){ red[(tid>>6)*2] = s1; red[(tid>>6)*2+1] = s2; }
  __syncthreads();
  s1 = red[0]+red[2]+red[4]+red[6];
  s2 = red[1]+red[3]+red[5]+red[7];
  float mu = s1 * (1.0f/Hd);
  float rstd = rsqrtf(s2*(1.0f/Hd) - mu*mu + 1e-12f);
  f32x4 wv = *(const f32x4*)(w + tid*4);
  f32x4 bv = *(const f32x4*)(bs + tid*4);
  s16x4 o;
  #pragma unroll
  for (int i=0;i<4;i++) o[i] = f2bf((v[i]-mu)*rstd*wv[i] + bv[i]);
  *(s16x4*)(h + (size_t)row*Hd + tid*4) = o;
}

// ---------------- W cast + transpose: [K=1024][N=3072] f32 -> [N][K] bf16 ----------------
__global__ __launch_bounds__(256) void castw_kernel(const float* __restrict__ w, short* __restrict__ wT){
  __shared__ float t[32][33];
  int n0 = blockIdx.x*32, k0 = blockIdx.y*32;
  int tx = threadIdx.x, ty = threadIdx.y;           // (32,8)
  #pragma unroll
  for (int i=0;i<4;i++) t[ty + i*8][tx] = w[(size_t)(k0 + ty + i*8)*N3 + n0 + tx];
  __syncthreads();
  #pragma unroll
  for (int i=0;i<4;i++) wT[(size_t)(n0 + ty + i*8)*Hd + k0 + tx] = f2bf(t[tx][ty + i*8]);
}

// ---------------- QKV GEMM + fused RoPE + V-transpose epilogue ----------------
// C[8192][3072] = h @ w + b. q/k written bf16 [bh][S][D] with RoPE applied
// (partner d^1 lives in lane^1 -> shfl_xor(x,1)); q pre-scaled by 1/8*log2e.
// v written directly transposed to [bh][D][S].
__global__ __launch_bounds__(256) void gemm_kernel(const short* __restrict__ A,
                                                   const short* __restrict__ Bt,
                                                   const float* __restrict__ bias,
                                                   const float* __restrict__ sp,
                                                   short* __restrict__ qo,
                                                   short* __restrict__ ko,
                                                   short* __restrict__ vo){
  __shared__ short lA[128*32];
  __shared__ short lB[128*32];
  int bid = blockIdx.x;
  int xcd = bid & 7, idx = bid >> 3;                 // idx 0..191
  int mt = xcd*8 + (idx & 7), nt = idx >> 3;         // mt 0..63, nt 0..23
  int m0 = mt*128, n0 = nt*128;
  int tid = threadIdx.x, lane = tid & 63, wv = tid >> 6;
  int l15 = lane & 15, lq = lane >> 4;
  int wr = wv >> 1, wc = wv & 1;
  f32x4 zero = {0.f,0.f,0.f,0.f};
  f32x4 acc[4][4];
  #pragma unroll
  for (int m=0;m<4;m++)
    #pragma unroll
    for (int n=0;n<4;n++) acc[m][n] = zero;
  int flat = tid*8;
  int row0 = flat >> 5, col0 = flat & 31;
  const short* ga = A  + (size_t)(m0 + row0)*Hd + col0;
  const short* gb = Bt + (size_t)(n0 + row0)*Hd + col0;
  short* lAw = lA + wv*512;
  short* lBw = lB + wv*512;
  for (int kk = 0; kk < Hd; kk += 32){
    __syncthreads();
    gld16(ga + kk,                 lAw);
    gld16(ga + kk + (size_t)64*Hd, lAw + 2048);
    gld16(gb + kk,                 lBw);
    gld16(gb + kk + (size_t)64*Hd, lBw + 2048);
    __syncthreads();
    s16x8 af[4], bf[4];
    #pragma unroll
    for (int m=0;m<4;m++) af[m] = *(const s16x8*)(lA + (wr*64 + m*16 + l15)*32 + 8*lq);
    #pragma unroll
    for (int n=0;n<4;n++) bf[n] = *(const s16x8*)(lB + (wc*64 + n*16 + l15)*32 + 8*lq);
    #pragma unroll
    for (int m=0;m<4;m++)
      #pragma unroll
      for (int n=0;n<4;n++)
        acc[m][n] = __builtin_amdgcn_mfma_f32_16x16x32_bf16(af[m], bf[n], acc[m][n], 0, 0, 0);
  }
  // ---- epilogue ----
  #pragma unroll
  for (int n=0;n<4;n++){
    int c = n0 + wc*64 + n*16 + l15;
    float bv = bias[c];
    int part = c >> 10, hh = (c >> 6) & 15, d = c & 63;
    if (part < 2){
      short* dst = part == 0 ? qo : ko;
      float sgnmul = (d & 1) ? 1.0f : -1.0f;        // even d: -x[d+1]*sin; odd d: +x[d-1]*sin
      float postscale = part == 0 ? 0.18033688011112042f : 1.0f;  // q: 1/sqrt(64)*log2(e)
      #pragma unroll
      for (int m=0;m<4;m++){
        #pragma unroll
        for (int j=0;j<4;j++){
          int r = m0 + wr*64 + m*16 + lq*4 + j;      // global row = b*2048 + s
          int b = r >> 11, s = r & 2047;
          float x = acc[m][n][j] + bv;
          float xp = __shfl_xor(x, 1);               // partner column d^1 (post-bias)
          const float* sr = sp + (size_t)s*64 + (d>>1);
          float y = (x*sr[32] + sgnmul*xp*sr[0]) * postscale;
          dst[(((size_t)((b*NHd + hh)*Sd + s)) << 6) + d] = f2bf(y);
        }
      }
    } else {
      #pragma unroll
      for (int m=0;m<4;m++){
        int r0 = m0 + wr*64 + m*16 + lq*4;           // 4 consecutive rows, same b
        int b = r0 >> 11, s0r = r0 & 2047;
        s16x4 o;
        #pragma unroll
        for (int j=0;j<4;j++) o[j] = f2bf(acc[m][n][j] + bv);
        *(s16x4*)(vo + (((size_t)((b*NHd + hh)*Dd + d)) << 11) + s0r) = o;
      }
    }
  }
}

// ---------------- Flash attention: 8 waves x 32 q-rows, KV stage 128 (2x64 halves) ----------------
// S^T = mfma(K, Q): lane owns q = lane&31. q pre-roped+scaled, k pre-roped by GEMM epilogue.
// K [128][64] and V^T [64][128] staged via global_load_lds, chunk-XOR swizzle on low 3 bits
// (both-sides, rule #21). One barrier per 128 kv. Softmax sums tree-reduced.
__global__ __launch_bounds__(512, 4) void attn_kernel(const short* __restrict__ q,
                                                      const short* __restrict__ k,
                                                      const short* __restrict__ vT,
                                                      float* __restrict__ out){
  __shared__ alignas(16) short kbuf[2][8192];        // [128 kv][64 d], swizzled (32 KB)
  __shared__ alignas(16) short vbuf[2][8192];        // [64 d][128 kv], swizzled (32 KB)
  int bid = blockIdx.x;
  int xcd = bid & 7, w = bid >> 3;                   // same-bh blocks share an XCD's L2
  int bh = xcd*8 + (w >> 3), qb = w & 7;
  int tid = threadIdx.x, lane = tid & 63, wv = tid >> 6;
  int l31 = lane & 31, hi = lane >> 5;
  const short* kp = k  + ((size_t)bh << 17);
  const short* vp = vT + ((size_t)bh << 17);
  int qrow = qb*256 + wv*32 + l31;
  const short* qp = q + ((size_t)bh << 17) + (size_t)qrow*64;
  s16x8 qf[4];                                       // B-frag: col=q(lane&31), k = d = 16*kk+8*hi+i
  #pragma unroll
  for (int kk=0;kk<4;kk++) qf[kk] = *(const s16x8*)(qp + kk*16 + hi*8);
  // ---- staging offsets (inverse-swizzled global source; LDS linear dest = tid*8 shorts/round) ----
  int kc0 = tid,      kr0 = kc0 >> 3;
  int kc1 = tid+512,  kr1 = kc1 >> 3;
  int koff0 = kr0*64 + ((kc0 ^ kr0) & 7)*8;
  int koff1 = kr1*64 + ((kc1 ^ kr1) & 7)*8;
  int vr0 = tid >> 4,       vcc0 = tid & 15;
  int vr1 = (tid+512) >> 4, vcc1 = (tid+512) & 15;
  int voff0 = vr0*2048 + ((vcc0 & 8) | ((vcc0 ^ vr0) & 7))*8;
  int voff1 = vr1*2048 + ((vcc1 & 8) | ((vcc1 ^ vr1) & 7))*8;

  f32x16 ot0 = z16(), ot1 = z16();                   // O^T: col=q, row = d
  float m = -1e30f, lr = 0.f;
  int rsw = (l31 & 7);                               // read-side chunk XOR

#define STAGE(nb, t) do { \
    gld16(kp + (size_t)(t)*8192 + koff0, &kbuf[nb][0]    + wv*512); \
    gld16(kp + (size_t)(t)*8192 + koff1, &kbuf[nb][4096] + wv*512); \
    gld16(vp + (size_t)(t)*128  + voff0, &vbuf[nb][0]    + wv*512); \
    gld16(vp + (size_t)(t)*128  + voff1, &vbuf[nb][4096] + wv*512); \
  } while(0)

  STAGE(0, 0);
  __syncthreads();

  for (int t = 0; t < 16; ++t){
    int cur = t & 1;
    if (t < 15) STAGE(cur^1, t+1);                   // drained by barrier at end of t
    #pragma unroll
    for (int h = 0; h < 2; ++h){
      const short* kb = &kbuf[cur][h*4096];
      const short* vb = &vbuf[cur][h*64];
      // ---- S^T = K . Q^T  (two 32x32 kv tiles, contraction d=64) ----
      f32x16 s0 = z16(), s1 = z16();
      __builtin_amdgcn_s_setprio(1);
      #pragma unroll
      for (int kk=0;kk<4;kk++){
        s16x8 kf0 = *(const s16x8*)(kb + l31*64       + (((kk*2 + hi) ^ rsw)*8));
        s0 = __builtin_amdgcn_mfma_f32_32x32x16_bf16(kf0, qf[kk], s0, 0, 0, 0);
        s16x8 kf1 = *(const s16x8*)(kb + (32+l31)*64  + (((kk*2 + hi) ^ rsw)*8));
        s1 = __builtin_amdgcn_mfma_f32_32x32x16_bf16(kf1, qf[kk], s1, 0, 0, 0);
      }
      __builtin_amdgcn_s_setprio(0);
      // ---- online softmax, lane-local per q-row (log2 domain) ----
      float tm[16];
      #pragma unroll
      for (int i=0;i<16;i++) tm[i] = fmaxf(s0[i], s1[i]);
      #pragma unroll
      for (int off=8; off>=1; off>>=1)
        #pragma unroll
        for (int i=0;i<off;i++) tm[i] = fmaxf(tm[i], tm[i+off]);
      float pmax = fmaxf(tm[0], __shfl_xor(tm[0], 32));
      if (!__all(pmax - m <= 8.0f)){                 // defer-max (T13)
        float mn = fmaxf(m, pmax);
        float al = fexp2(m - mn);
        m = mn; lr *= al;
        #pragma unroll
        for (int i=0;i<16;i++){ ot0[i] *= al; ot1[i] *= al; }
      }
      #pragma unroll
      for (int i=0;i<16;i++){ s0[i] = fexp2(s0[i]-m); s1[i] = fexp2(s1[i]-m); }
      float ra[16];
      #pragma unroll
      for (int i=0;i<16;i++) ra[i] = s0[i] + s1[i];
      #pragma unroll
      for (int off=8; off>=1; off>>=1)
        #pragma unroll
        for (int i=0;i<off;i++) ra[i] += ra[i+off];
      lr += ra[0] + __shfl_xor(ra[0], 32);
      // ---- P^T -> bf16 B-frags, O^T += V^T . P^T ----
      #pragma unroll
      for (int s4=0;s4<4;s4++){
        int base = (s4 & 1) * 8;
        int pkA0, pkA1, pkB0, pkB1;
        if (s4 < 2){
          pkA0 = cvtpk(s0[base],   s0[base+1]); pkA1 = cvtpk(s0[base+2], s0[base+3]);
          pkB0 = cvtpk(s0[base+4], s0[base+5]); pkB1 = cvtpk(s0[base+6], s0[base+7]);
        } else {
          pkA0 = cvtpk(s1[base],   s1[base+1]); pkA1 = cvtpk(s1[base+2], s1[base+3]);
          pkB0 = cvtpk(s1[base+4], s1[base+5]); pkB1 = cvtpk(s1[base+6], s1[base+7]);
        }
        int r0 = __shfl_xor(hi ? pkA0 : pkB0, 32);
        int r1 = __shfl_xor(hi ? pkA1 : pkB1, 32);
        union { int wq[4]; s16x8 v8; } u;
        u.wq[0] = hi ? r0   : pkA0;
        u.wq[1] = hi ? r1   : pkA1;
        u.wq[2] = hi ? pkB0 : r0;
        u.wq[3] = hi ? pkB1 : r1;
        __builtin_amdgcn_s_setprio(1);
        s16x8 vf0 = *(const s16x8*)(vb + l31*128      + (((s4*2 + hi) ^ rsw)*8));
        ot0 = __builtin_amdgcn_mfma_f32_32x32x16_bf16(vf0, u.v8, ot0, 0, 0, 0);
        s16x8 vf1 = *(const s16x8*)(vb + (32+l31)*128 + (((s4*2 + hi) ^ rsw)*8));
        ot1 = __builtin_amdgcn_mfma_f32_32x32x16_bf16(vf1, u.v8, ot1, 0, 0, 0);
        __builtin_amdgcn_s_setprio(0);
      }
    }
    __syncthreads();                                 // drains vmcnt (stage) + all waves done with cur
  }
#undef STAGE
  // ---- epilogue: out[b][s=q][h*64 + d], d = 8g + 4hi + j (+32 for db=1) ----
  float inv = 1.0f / lr;
  int b = bh >> 4, hh = bh & 15;
  float* orow = out + ((size_t)(b*Sd + qrow) << 10) + hh*64;
  #pragma unroll
  for (int g=0; g<4; ++g){
    f32x4 w0, w1;
    #pragma unroll
    for (int j=0;j<4;j++){ w0[j] = ot0[4*g+j]*inv; w1[j] = ot1[4*g+j]*inv; }
    *(f32x4*)(orow + g*8 + 4*hi)      = w0;
    *(f32x4*)(orow + 32 + g*8 + 4*hi) = w1;
  }
}

extern "C" void kernel_launch(void* const* d_in, const int* in_sizes, int n_in,
                              void* d_out, int out_size, void* d_ws, size_t ws_size,
                              hipStream_t stream){
  const float* hs = (const float*)d_in[0];
  const float* sp = (const float*)d_in[1];
  const float* lw = (const float*)d_in[2];
  const float* lb = (const float*)d_in[3];
  const float* wq = (const float*)d_in[4];
  const float* bq = (const float*)d_in[5];
  float* out = (float*)d_out;
  char* ws = (char*)d_ws;
  short* h   = (short*)(ws);
  short* wT  = (short*)(ws + 16777216);
  short* qb_ = (short*)(ws + 23068672);
  short* kb_ = (short*)(ws + 23068672 + 16777216);
  short* vTb = (short*)(ws + 23068672 + 33554432);   // [bh][D][S], written by GEMM epilogue

  hipLaunchKernelGGL(ln_kernel,    dim3(8192),    dim3(256),   0, stream, hs, lw, lb, h);
  hipLaunchKernelGGL(castw_kernel, dim3(96,32),   dim3(32,8),  0, stream, wq, wT);
  hipLaunchKernelGGL(gemm_kernel,  dim3(1536),    dim3(256),   0, stream, h, wT, bq, sp, qb_, kb_, vTb);
  hipLaunchKernelGGL(attn_kernel,  dim3(512),     dim3(512),   0, stream, qb_, kb_, vTb, out);
}

// Round 7
// 187.110 us; speedup vs baseline: 1.1365x; 1.0069x over previous
//
#include <hip/hip_runtime.h>
#include <hip/hip_bf16.h>
#include <cstdint>
#include <cstddef>

#define DEVINL __device__ __forceinline__

typedef float f32x4 __attribute__((ext_vector_type(4)));
typedef float f32x16 __attribute__((ext_vector_type(16)));
typedef short s16x8 __attribute__((ext_vector_type(8)));
typedef short s16x4 __attribute__((ext_vector_type(4)));

static constexpr int Sd = 2048;   // sequence
static constexpr int Hd = 1024;   // hidden
static constexpr int NHd = 16;    // heads
static constexpr int Dd = 64;    // head dim
static constexpr int N3 = 3072;   // 3*H

DEVINL float bf2f(short u){
  unsigned int t = ((unsigned int)(unsigned short)u) << 16;
  float f; __builtin_memcpy(&f, &t, 4); return f;
}
DEVINL short f2bf(float f){
  unsigned int t; __builtin_memcpy(&t, &f, 4);
  unsigned int r = t + 0x7FFFu + ((t >> 16) & 1u);   // RNE
  return (short)(r >> 16);
}

DEVINL void gld16(const short* g, short* l){
  __builtin_amdgcn_global_load_lds((const __attribute__((address_space(1))) unsigned int*)g,
                                   (__attribute__((address_space(3))) unsigned int*)l, 16, 0, 0);
}

DEVINL int cvtpk(float lo, float hi){
  int r; asm("v_cvt_pk_bf16_f32 %0, %1, %2" : "=v"(r) : "v"(lo), "v"(hi)); return r;
}

DEVINL float fexp2(float x){
#if __has_builtin(__builtin_amdgcn_exp2f)
  return __builtin_amdgcn_exp2f(x);
#else
  return exp2f(x);
#endif
}

DEVINL f32x16 z16(){
  f32x16 v;
  #pragma unroll
  for (int i=0;i<16;i++) v[i]=0.f;
  return v;
}

// ---------------- LayerNorm + cast to bf16 ----------------
__global__ __launch_bounds__(256) void ln_kernel(const float* __restrict__ x,
                                                 const float* __restrict__ w,
                                                 const float* __restrict__ bs,
                                                 short* __restrict__ h){
  int row = blockIdx.x, tid = threadIdx.x;          // 8192 rows, 4 f32/thread
  const float* xr = x + (size_t)row * Hd;
  f32x4 v = *(const f32x4*)(xr + tid*4);
  float s1 = v[0]+v[1]+v[2]+v[3];
  float s2 = v[0]*v[0]+v[1]*v[1]+v[2]*v[2]+v[3]*v[3];
  #pragma unroll
  for (int off = 1; off < 64; off <<= 1){ s1 += __shfl_xor(s1, off); s2 += __shfl_xor(s2, off); }
  __shared__ float red[8];
  if ((tid & 63) == 0){ red[(tid>>6)*2] = s1; red[(tid>>6)*2+1] = s2; }
  __syncthreads();
  s1 = red[0]+red[2]+red[4]+red[6];
  s2 = red[1]+red[3]+red[5]+red[7];
  float mu = s1 * (1.0f/Hd);
  float rstd = rsqrtf(s2*(1.0f/Hd) - mu*mu + 1e-12f);
  f32x4 wv = *(const f32x4*)(w + tid*4);
  f32x4 bv = *(const f32x4*)(bs + tid*4);
  s16x4 o;
  #pragma unroll
  for (int i=0;i<4;i++) o[i] = f2bf((v[i]-mu)*rstd*wv[i] + bv[i]);
  *(s16x4*)(h + (size_t)row*Hd + tid*4) = o;
}

// ---------------- W cast + transpose: [K=1024][N=3072] f32 -> [N][K] bf16 ----------------
__global__ __launch_bounds__(256) void castw_kernel(const float* __restrict__ w, short* __restrict__ wT){
  __shared__ float t[32][33];
  int n0 = blockIdx.x*32, k0 = blockIdx.y*32;
  int tx = threadIdx.x, ty = threadIdx.y;           // (32,8)
  #pragma unroll
  for (int i=0;i<4;i++) t[ty + i*8][tx] = w[(size_t)(k0 + ty + i*8)*N3 + n0 + tx];
  __syncthreads();
  #pragma unroll
  for (int i=0;i<4;i++) wT[(size_t)(n0 + ty + i*8)*Hd + k0 + tx] = f2bf(t[tx][ty + i*8]);
}

// ---------------- QKV GEMM + fused RoPE + V-transpose epilogue ----------------
// C[8192][3072] = h @ w + b. Blocks are part-pure (nt>>3 -> q/k/v). q/k written bf16
// [bh][S][D] with RoPE applied (partner d^1 lives in lane^1 -> shfl_xor(x,1)); q
// pre-scaled by 1/8*log2e. v written directly transposed to [bh][D][S].
// sin/cos for the block's 128 rows staged to LDS (32 KB, aliases dead lA/lB) to
// avoid the R6 scalar-VMEM storm (2 global loads per element -> 2 LDS reads).
__global__ __launch_bounds__(256) void gemm_kernel(const short* __restrict__ A,
                                                   const short* __restrict__ Bt,
                                                   const float* __restrict__ bias,
                                                   const float* __restrict__ sp,
                                                   short* __restrict__ qo,
                                                   short* __restrict__ ko,
                                                   short* __restrict__ vo){
  __shared__ alignas(16) char smem[32768];
  short* lA = (short*)smem;                          // [128*32] bf16 (8 KB)
  short* lB = (short*)(smem + 8192);                 // [128*32] bf16 (8 KB)
  float* sps = (float*)smem;                         // [128][64] f32, epilogue only
  int bid = blockIdx.x;
  int xcd = bid & 7, idx = bid >> 3;                 // idx 0..191
  int mt = xcd*8 + (idx & 7), nt = idx >> 3;         // mt 0..63, nt 0..23
  int m0 = mt*128, n0 = nt*128;
  int tid = threadIdx.x, lane = tid & 63, wv = tid >> 6;
  int l15 = lane & 15, lq = lane >> 4;
  int wr = wv >> 1, wc = wv & 1;
  f32x4 zero = {0.f,0.f,0.f,0.f};
  f32x4 acc[4][4];
  #pragma unroll
  for (int m=0;m<4;m++)
    #pragma unroll
    for (int n=0;n<4;n++) acc[m][n] = zero;
  int flat = tid*8;
  int row0 = flat >> 5, col0 = flat & 31;
  const short* ga = A  + (size_t)(m0 + row0)*Hd + col0;
  const short* gb = Bt + (size_t)(n0 + row0)*Hd + col0;
  short* lAw = lA + wv*512;
  short* lBw = lB + wv*512;
  for (int kk = 0; kk < Hd; kk += 32){
    __syncthreads();
    gld16(ga + kk,                 lAw);
    gld16(ga + kk + (size_t)64*Hd, lAw + 2048);
    gld16(gb + kk,                 lBw);
    gld16(gb + kk + (size_t)64*Hd, lBw + 2048);
    __syncthreads();
    s16x8 af[4], bf[4];
    #pragma unroll
    for (int m=0;m<4;m++) af[m] = *(const s16x8*)(lA + (wr*64 + m*16 + l15)*32 + 8*lq);
    #pragma unroll
    for (int n=0;n<4;n++) bf[n] = *(const s16x8*)(lB + (wc*64 + n*16 + l15)*32 + 8*lq);
    #pragma unroll
    for (int m=0;m<4;m++)
      #pragma unroll
      for (int n=0;n<4;n++)
        acc[m][n] = __builtin_amdgcn_mfma_f32_16x16x32_bf16(af[m], bf[n], acc[m][n], 0, 0, 0);
  }
  // ---- epilogue (block-uniform part) ----
  int part = nt >> 3;                                // 0:q 1:k 2:v
  if (part == 2){
    #pragma unroll
    for (int n=0;n<4;n++){
      int c = n0 + wc*64 + n*16 + l15;
      float bv = bias[c];
      int hh = (c >> 6) & 15, d = c & 63;
      #pragma unroll
      for (int m=0;m<4;m++){
        int r0 = m0 + wr*64 + m*16 + lq*4;           // 4 consecutive rows, same b
        int b = r0 >> 11, s0r = r0 & 2047;
        s16x4 o;
        #pragma unroll
        for (int j=0;j<4;j++) o[j] = f2bf(acc[m][n][j] + bv);
        *(s16x4*)(vo + (((size_t)((b*NHd + hh)*Dd + d)) << 11) + s0r) = o;
      }
    }
  } else {
    __syncthreads();                                 // lA/lB reads complete in all waves
    const float* gsp = sp + (size_t)(m0 & 2047)*64;  // block's 128 rows of sin/cos
    #pragma unroll
    for (int i=0;i<8;i++)
      *(f32x4*)(sps + i*1024 + tid*4) = *(const f32x4*)(gsp + i*1024 + tid*4);
    __syncthreads();
    short* dst = part == 0 ? qo : ko;
    float postscale = part == 0 ? 0.18033688011112042f : 1.0f;  // q: 1/sqrt(64)*log2(e)
    #pragma unroll
    for (int n=0;n<4;n++){
      int c = n0 + wc*64 + n*16 + l15;
      float bv = bias[c];
      int hh = (c >> 6) & 15, d = c & 63;
      float sgnmul = (d & 1) ? 1.0f : -1.0f;         // even d: -x[d+1]*sin; odd d: +x[d-1]*sin
      #pragma unroll
      for (int m=0;m<4;m++){
        #pragma unroll
        for (int j=0;j<4;j++){
          int sl = wr*64 + m*16 + lq*4 + j;          // local row 0..127
          float x = acc[m][n][j] + bv;
          float xp = __shfl_xor(x, 1);               // partner column d^1 (post-bias)
          const float* sr = sps + sl*64 + (d>>1);
          float y = (x*sr[32] + sgnmul*xp*sr[0]) * postscale;
          int r = m0 + sl;
          int b = r >> 11, s = r & 2047;
          dst[(((size_t)((b*NHd + hh)*Sd + s)) << 6) + d] = f2bf(y);
        }
      }
    }
  }
}

// ---------------- Flash attention: 8 waves x 32 q-rows, KV stage 128 (2x64 halves) ----------------
// S^T = mfma(K, Q): lane owns q = lane&31. q pre-roped+scaled, k pre-roped by GEMM epilogue.
// K [128][64] and V^T [64][128] staged via global_load_lds, chunk-XOR swizzle on low 3 bits
// (both-sides, rule #21). One barrier per 128 kv. Softmax sums tree-reduced.
__global__ __launch_bounds__(512, 4) void attn_kernel(const short* __restrict__ q,
                                                      const short* __restrict__ k,
                                                      const short* __restrict__ vT,
                                                      float* __restrict__ out){
  __shared__ alignas(16) short kbuf[2][8192];        // [128 kv][64 d], swizzled (32 KB)
  __shared__ alignas(16) short vbuf[2][8192];        // [64 d][128 kv], swizzled (32 KB)
  int bid = blockIdx.x;
  int xcd = bid & 7, w = bid >> 3;                   // same-bh blocks share an XCD's L2
  int bh = xcd*8 + (w >> 3), qb = w & 7;
  int tid = threadIdx.x, lane = tid & 63, wv = tid >> 6;
  int l31 = lane & 31, hi = lane >> 5;
  const short* kp = k  + ((size_t)bh << 17);
  const short* vp = vT + ((size_t)bh << 17);
  int qrow = qb*256 + wv*32 + l31;
  const short* qp = q + ((size_t)bh << 17) + (size_t)qrow*64;
  s16x8 qf[4];                                       // B-frag: col=q(lane&31), k = d = 16*kk+8*hi+i
  #pragma unroll
  for (int kk=0;kk<4;kk++) qf[kk] = *(const s16x8*)(qp + kk*16 + hi*8);
  // ---- staging offsets (inverse-swizzled global source; LDS linear dest = tid*8 shorts/round) ----
  int kc0 = tid,      kr0 = kc0 >> 3;
  int kc1 = tid+512,  kr1 = kc1 >> 3;
  int koff0 = kr0*64 + ((kc0 ^ kr0) & 7)*8;
  int koff1 = kr1*64 + ((kc1 ^ kr1) & 7)*8;
  int vr0 = tid >> 4,       vcc0 = tid & 15;
  int vr1 = (tid+512) >> 4, vcc1 = (tid+512) & 15;
  int voff0 = vr0*2048 + ((vcc0 & 8) | ((vcc0 ^ vr0) & 7))*8;
  int voff1 = vr1*2048 + ((vcc1 & 8) | ((vcc1 ^ vr1) & 7))*8;

  f32x16 ot0 = z16(), ot1 = z16();                   // O^T: col=q, row = d
  float m = -1e30f, lr = 0.f;
  int rsw = (l31 & 7);                               // read-side chunk XOR

#define STAGE(nb, t) do { \
    gld16(kp + (size_t)(t)*8192 + koff0, &kbuf[nb][0]    + wv*512); \
    gld16(kp + (size_t)(t)*8192 + koff1, &kbuf[nb][4096] + wv*512); \
    gld16(vp + (size_t)(t)*128  + voff0, &vbuf[nb][0]    + wv*512); \
    gld16(vp + (size_t)(t)*128  + voff1, &vbuf[nb][4096] + wv*512); \
  } while(0)

  STAGE(0, 0);
  __syncthreads();

  for (int t = 0; t < 16; ++t){
    int cur = t & 1;
    if (t < 15) STAGE(cur^1, t+1);                   // drained by barrier at end of t
    #pragma unroll
    for (int h = 0; h < 2; ++h){
      const short* kb = &kbuf[cur][h*4096];
      const short* vb = &vbuf[cur][h*64];
      // ---- S^T = K . Q^T  (two 32x32 kv tiles, contraction d=64) ----
      f32x16 s0 = z16(), s1 = z16();
      __builtin_amdgcn_s_setprio(1);
      #pragma unroll
      for (int kk=0;kk<4;kk++){
        s16x8 kf0 = *(const s16x8*)(kb + l31*64       + (((kk*2 + hi) ^ rsw)*8));
        s0 = __builtin_amdgcn_mfma_f32_32x32x16_bf16(kf0, qf[kk], s0, 0, 0, 0);
        s16x8 kf1 = *(const s16x8*)(kb + (32+l31)*64  + (((kk*2 + hi) ^ rsw)*8));
        s1 = __builtin_amdgcn_mfma_f32_32x32x16_bf16(kf1, qf[kk], s1, 0, 0, 0);
      }
      __builtin_amdgcn_s_setprio(0);
      // ---- online softmax, lane-local per q-row (log2 domain) ----
      float tm[16];
      #pragma unroll
      for (int i=0;i<16;i++) tm[i] = fmaxf(s0[i], s1[i]);
      #pragma unroll
      for (int off=8; off>=1; off>>=1)
        #pragma unroll
        for (int i=0;i<off;i++) tm[i] = fmaxf(tm[i], tm[i+off]);
      float pmax = fmaxf(tm[0], __shfl_xor(tm[0], 32));
      if (!__all(pmax - m <= 8.0f)){                 // defer-max (T13)
        float mn = fmaxf(m, pmax);
        float al = fexp2(m - mn);
        m = mn; lr *= al;
        #pragma unroll
        for (int i=0;i<16;i++){ ot0[i] *= al; ot1[i] *= al; }
      }
      #pragma unroll
      for (int i=0;i<16;i++){ s0[i] = fexp2(s0[i]-m); s1[i] = fexp2(s1[i]-m); }
      float ra[16];
      #pragma unroll
      for (int i=0;i<16;i++) ra[i] = s0[i] + s1[i];
      #pragma unroll
      for (int off=8; off>=1; off>>=1)
        #pragma unroll
        for (int i=0;i<off;i++) ra[i] += ra[i+off];
      lr += ra[0] + __shfl_xor(ra[0], 32);
      // ---- P^T -> bf16 B-frags, O^T += V^T . P^T ----
      #pragma unroll
      for (int s4=0;s4<4;s4++){
        int base = (s4 & 1) * 8;
        int pkA0, pkA1, pkB0, pkB1;
        if (s4 < 2){
          pkA0 = cvtpk(s0[base],   s0[base+1]); pkA1 = cvtpk(s0[base+2], s0[base+3]);
          pkB0 = cvtpk(s0[base+4], s0[base+5]); pkB1 = cvtpk(s0[base+6], s0[base+7]);
        } else {
          pkA0 = cvtpk(s1[base],   s1[base+1]); pkA1 = cvtpk(s1[base+2], s1[base+3]);
          pkB0 = cvtpk(s1[base+4], s1[base+5]); pkB1 = cvtpk(s1[base+6], s1[base+7]);
        }
        int r0 = __shfl_xor(hi ? pkA0 : pkB0, 32);
        int r1 = __shfl_xor(hi ? pkA1 : pkB1, 32);
        union { int wq[4]; s16x8 v8; } u;
        u.wq[0] = hi ? r0   : pkA0;
        u.wq[1] = hi ? r1   : pkA1;
        u.wq[2] = hi ? pkB0 : r0;
        u.wq[3] = hi ? pkB1 : r1;
        __builtin_amdgcn_s_setprio(1);
        s16x8 vf0 = *(const s16x8*)(vb + l31*128      + (((s4*2 + hi) ^ rsw)*8));
        ot0 = __builtin_amdgcn_mfma_f32_32x32x16_bf16(vf0, u.v8, ot0, 0, 0, 0);
        s16x8 vf1 = *(const s16x8*)(vb + (32+l31)*128 + (((s4*2 + hi) ^ rsw)*8));
        ot1 = __builtin_amdgcn_mfma_f32_32x32x16_bf16(vf1, u.v8, ot1, 0, 0, 0);
        __builtin_amdgcn_s_setprio(0);
      }
    }
    __syncthreads();                                 // drains vmcnt (stage) + all waves done with cur
  }
#undef STAGE
  // ---- epilogue: out[b][s=q][h*64 + d], d = 8g + 4hi + j (+32 for db=1) ----
  float inv = 1.0f / lr;
  int b = bh >> 4, hh = bh & 15;
  float* orow = out + ((size_t)(b*Sd + qrow) << 10) + hh*64;
  #pragma unroll
  for (int g=0; g<4; ++g){
    f32x4 w0, w1;
    #pragma unroll
    for (int j=0;j<4;j++){ w0[j] = ot0[4*g+j]*inv; w1[j] = ot1[4*g+j]*inv; }
    *(f32x4*)(orow + g*8 + 4*hi)      = w0;
    *(f32x4*)(orow + 32 + g*8 + 4*hi) = w1;
  }
}

extern "C" void kernel_launch(void* const* d_in, const int* in_sizes, int n_in,
                              void* d_out, int out_size, void* d_ws, size_t ws_size,
                              hipStream_t stream){
  const float* hs = (const float*)d_in[0];
  const float* sp = (const float*)d_in[1];
  const float* lw = (const float*)d_in[2];
  const float* lb = (const float*)d_in[3];
  const float* wq = (const float*)d_in[4];
  const float* bq = (const float*)d_in[5];
  float* out = (float*)d_out;
  char* ws = (char*)d_ws;
  short* h   = (short*)(ws);
  short* wT  = (short*)(ws + 16777216);
  short* qb_ = (short*)(ws + 23068672);
  short* kb_ = (short*)(ws + 23068672 + 16777216);
  short* vTb = (short*)(ws + 23068672 + 33554432);   // [bh][D][S], written by GEMM epilogue

  hipLaunchKernelGGL(ln_kernel,    dim3(8192),    dim3(256),   0, stream, hs, lw, lb, h);
  hipLaunchKernelGGL(castw_kernel, dim3(96,32),   dim3(32,8),  0, stream, wq, wT);
  hipLaunchKernelGGL(gemm_kernel,  dim3(1536),    dim3(256),   0, stream, h, wT, bq, sp, qb_, kb_, vTb);
  hipLaunchKernelGGL(attn_kernel,  dim3(512),     dim3(512),   0, stream, qb_, kb_, vTb, out);
}

// Round 10
// 186.313 us; speedup vs baseline: 1.1414x; 1.0043x over previous
//
#include <hip/hip_runtime.h>
#include <hip/hip_bf16.h>
#include <cstdint>
#include <cstddef>

#define DEVINL __device__ __forceinline__

typedef float f32x2 __attribute__((ext_vector_type(2)));
typedef float f32x4 __attribute__((ext_vector_type(4)));
typedef float f32x16 __attribute__((ext_vector_type(16)));
typedef short s16x8 __attribute__((ext_vector_type(8)));
typedef short s16x4 __attribute__((ext_vector_type(4)));

static constexpr int Sd = 2048;   // sequence
static constexpr int Hd = 1024;   // hidden
static constexpr int NHd = 16;    // heads
static constexpr int Dd = 64;     // head dim
static constexpr int N3 = 3072;   // 3*H

DEVINL float bf2f(short u){
  unsigned int t = ((unsigned int)(unsigned short)u) << 16;
  float f; __builtin_memcpy(&f, &t, 4); return f;
}
DEVINL short f2bf(float f){
  unsigned int t; __builtin_memcpy(&t, &f, 4);
  unsigned int r = t + 0x7FFFu + ((t >> 16) & 1u);   // RNE
  return (short)(r >> 16);
}

DEVINL void gld16(const short* g, short* l){
  __builtin_amdgcn_global_load_lds((const __attribute__((address_space(1))) unsigned int*)g,
                                   (__attribute__((address_space(3))) unsigned int*)l, 16, 0, 0);
}

DEVINL int cvtpk(float lo, float hi){
  int r; asm("v_cvt_pk_bf16_f32 %0, %1, %2" : "=v"(r) : "v"(lo), "v"(hi)); return r;
}

DEVINL float fexp2(float x){
#if __has_builtin(__builtin_amdgcn_exp2f)
  return __builtin_amdgcn_exp2f(x);
#else
  return exp2f(x);
#endif
}

DEVINL f32x16 z16(){
  f32x16 v;
  #pragma unroll
  for (int i=0;i<16;i++) v[i]=0.f;
  return v;
}

// ---------------- LayerNorm + cast to bf16 ----------------
__global__ __launch_bounds__(256) void ln_kernel(const float* __restrict__ x,
                                                 const float* __restrict__ w,
                                                 const float* __restrict__ bs,
                                                 short* __restrict__ h){
  int row = blockIdx.x, tid = threadIdx.x;          // 8192 rows, 4 f32/thread
  const float* xr = x + (size_t)row * Hd;
  f32x4 v = *(const f32x4*)(xr + tid*4);
  float s1 = v[0]+v[1]+v[2]+v[3];
  float s2 = v[0]*v[0]+v[1]*v[1]+v[2]*v[2]+v[3]*v[3];
  #pragma unroll
  for (int off = 1; off < 64; off <<= 1){ s1 += __shfl_xor(s1, off); s2 += __shfl_xor(s2, off); }
  __shared__ float red[8];
  if ((tid & 63) == 0){ red[(tid>>6)*2] = s1; red[(tid>>6)*2+1] = s2; }
  __syncthreads();
  s1 = red[0]+red[2]+red[4]+red[6];
  s2 = red[1]+red[3]+red[5]+red[7];
  float mu = s1 * (1.0f/Hd);
  float rstd = rsqrtf(s2*(1.0f/Hd) - mu*mu + 1e-12f);
  f32x4 wv = *(const f32x4*)(w + tid*4);
  f32x4 bv = *(const f32x4*)(bs + tid*4);
  s16x4 o;
  #pragma unroll
  for (int i=0;i<4;i++) o[i] = f2bf((v[i]-mu)*rstd*wv[i] + bv[i]);
  *(s16x4*)(h + (size_t)row*Hd + tid*4) = o;
}

// ---------------- W cast + transpose: [K=1024][N=3072] f32 -> [N][K] bf16 ----------------
__global__ __launch_bounds__(256) void castw_kernel(const float* __restrict__ w, short* __restrict__ wT){
  __shared__ float t[32][33];
  int n0 = blockIdx.x*32, k0 = blockIdx.y*32;
  int tx = threadIdx.x, ty = threadIdx.y;           // (32,8)
  #pragma unroll
  for (int i=0;i<4;i++) t[ty + i*8][tx] = w[(size_t)(k0 + ty + i*8)*N3 + n0 + tx];
  __syncthreads();
  #pragma unroll
  for (int i=0;i<4;i++) wT[(size_t)(n0 + ty + i*8)*Hd + k0 + tx] = f2bf(t[tx][ty + i*8]);
}

// ---------------- QKV GEMM + fused RoPE + V-transpose epilogue ----------------
// C[8192][3072] = h @ w + b. Blocks are part-pure (nt>>3 -> q/k/v). q/k written bf16
// [bh][S][D] with RoPE (partner d^1 in lane^1 -> shfl_xor(x,1)); q pre-scaled by
// 1/8*log2e. v written transposed to [bh][D][S]. sin/cos staged to LDS interleaved
// as (sin,cos) f32 pairs, row stride 66 f32. d = (wc*64+n*16+l15) & 63, so
// d>>1 = n*8 + (l15>>1) -- no wc term.
__global__ __launch_bounds__(256) void gemm_kernel(const short* __restrict__ A,
                                                   const short* __restrict__ Bt,
                                                   const float* __restrict__ bias,
                                                   const float* __restrict__ sp,
                                                   short* __restrict__ qo,
                                                   short* __restrict__ ko,
                                                   short* __restrict__ vo){
  __shared__ alignas(16) char smem[33792];           // max(lA+lB 16KB, sps2 [128][66] f32)
  short* lA = (short*)smem;                          // [128*32] bf16 (8 KB)
  short* lB = (short*)(smem + 8192);                 // [128*32] bf16 (8 KB)
  float* sps2 = (float*)smem;                        // [128][66] f32 interleaved pairs
  int bid = blockIdx.x;
  int xcd = bid & 7, idx = bid >> 3;                 // idx 0..191
  int mt = xcd*8 + (idx & 7), nt = idx >> 3;         // mt 0..63, nt 0..23
  int m0 = mt*128, n0 = nt*128;
  int tid = threadIdx.x, lane = tid & 63, wv = tid >> 6;
  int l15 = lane & 15, lq = lane >> 4;
  int wr = wv >> 1, wc = wv & 1;
  f32x4 zero = {0.f,0.f,0.f,0.f};
  f32x4 acc[4][4];
  #pragma unroll
  for (int m=0;m<4;m++)
    #pragma unroll
    for (int n=0;n<4;n++) acc[m][n] = zero;
  int flat = tid*8;
  int row0 = flat >> 5, col0 = flat & 31;
  const short* ga = A  + (size_t)(m0 + row0)*Hd + col0;
  const short* gb = Bt + (size_t)(n0 + row0)*Hd + col0;
  short* lAw = lA + wv*512;
  short* lBw = lB + wv*512;
  for (int kk = 0; kk < Hd; kk += 32){
    __syncthreads();
    gld16(ga + kk,                 lAw);
    gld16(ga + kk + (size_t)64*Hd, lAw + 2048);
    gld16(gb + kk,                 lBw);
    gld16(gb + kk + (size_t)64*Hd, lBw + 2048);
    __syncthreads();
    s16x8 af[4], bf[4];
    #pragma unroll
    for (int m=0;m<4;m++) af[m] = *(const s16x8*)(lA + (wr*64 + m*16 + l15)*32 + 8*lq);
    #pragma unroll
    for (int n=0;n<4;n++) bf[n] = *(const s16x8*)(lB + (wc*64 + n*16 + l15)*32 + 8*lq);
    #pragma unroll
    for (int m=0;m<4;m++)
      #pragma unroll
      for (int n=0;n<4;n++)
        acc[m][n] = __builtin_amdgcn_mfma_f32_16x16x32_bf16(af[m], bf[n], acc[m][n], 0, 0, 0);
  }
  // ---- epilogue (block-uniform part) ----
  int part = nt >> 3;                                // 0:q 1:k 2:v
  if (part == 2){
    #pragma unroll
    for (int n=0;n<4;n++){
      int c = n0 + wc*64 + n*16 + l15;
      float bv = bias[c];
      int hh = (c >> 6) & 15, d = c & 63;
      #pragma unroll
      for (int m=0;m<4;m++){
        int r0 = m0 + wr*64 + m*16 + lq*4;           // 4 consecutive rows, same b
        int b = r0 >> 11, s0r = r0 & 2047;
        s16x4 o;
        #pragma unroll
        for (int j=0;j<4;j++) o[j] = f2bf(acc[m][n][j] + bv);
        *(s16x4*)(vo + (((size_t)((b*NHd + hh)*Dd + d)) << 11) + s0r) = o;
      }
    }
  } else {
    __syncthreads();                                 // lA/lB reads complete in all waves
    const float* gsp = sp + (size_t)(m0 & 2047)*64;  // block's 128 rows of sin/cos
    // stage interleaved: sps2[sl*66 + 2*dh] = sin, +1 = cos   (1024 units of 4 dh)
    #pragma unroll
    for (int u4=0; u4<4; ++u4){
      int u = tid + u4*256;
      int sl = u >> 3, dh4 = u & 7;
      f32x4 s4v = *(const f32x4*)(gsp + sl*64 + dh4*4);
      f32x4 c4v = *(const f32x4*)(gsp + sl*64 + 32 + dh4*4);
      float* w8 = sps2 + sl*66 + dh4*8;
      f32x2 p0 = {s4v[0], c4v[0]}, p1 = {s4v[1], c4v[1]};
      f32x2 p2 = {s4v[2], c4v[2]}, p3 = {s4v[3], c4v[3]};
      *(f32x2*)(w8)     = p0; *(f32x2*)(w8 + 2) = p1;
      *(f32x2*)(w8 + 4) = p2; *(f32x2*)(w8 + 6) = p3;
    }
    __syncthreads();
    short* dst = part == 0 ? qo : ko;
    float postscale = part == 0 ? 0.18033688011112042f : 1.0f;  // q: 1/sqrt(64)*log2(e)
    float sgnmul = (l15 & 1) ? 1.0f : -1.0f;         // d parity == l15 parity
    float bvv[4]; int hhv[4], dv[4];
    #pragma unroll
    for (int n=0;n<4;n++){
      int c = n0 + wc*64 + n*16 + l15;
      bvv[n] = bias[c]; hhv[n] = (c >> 6) & 15; dv[n] = c & 63;
    }
    int dh0 = l15 >> 1;                              // d>>1 = n*8 + (l15>>1)
    #pragma unroll
    for (int m=0;m<4;m++){
      #pragma unroll
      for (int j=0;j<4;j++){
        int sl = wr*64 + m*16 + lq*4 + j;            // local row 0..127
        const float* sb = sps2 + sl*66 + dh0*2;
        int r = m0 + sl;
        int b = r >> 11, s = r & 2047;
        #pragma unroll
        for (int n=0;n<4;n++){
          f32x2 sc = *(const f32x2*)(sb + n*16);     // (sin, cos) for d = n*16+l15
          float x = acc[m][n][j] + bvv[n];
          float xp = __shfl_xor(x, 1);               // partner column d^1 (post-bias)
          float y = (x*sc[1] + sgnmul*xp*sc[0]) * postscale;
          dst[(((size_t)((b*NHd + hhv[n])*Sd + s)) << 6) + dv[n]] = f2bf(y);
        }
      }
    }
  }
}

// ---------------- Flash attention: 8 waves x 32 q-rows, KV stage 128 (2x64 halves) ----------------
// S^T = mfma(K, Q): lane owns q = lane&31. q pre-roped+scaled, k pre-roped by GEMM epilogue.
// DEFER-MAX online softmax (R7-proven; R8/R9's fixed-offset variant failed validation at
// 3.4e-2 -- numerics mechanism unexplained, do not retry without a probe).
__global__ __launch_bounds__(512, 4) void attn_kernel(const short* __restrict__ q,
                                                      const short* __restrict__ k,
                                                      const short* __restrict__ vT,
                                                      float* __restrict__ out){
  __shared__ alignas(16) short kbuf[2][8192];        // [128 kv][64 d], swizzled (32 KB)
  __shared__ alignas(16) short vbuf[2][8192];        // [64 d][128 kv], swizzled (32 KB)
  int bid = blockIdx.x;
  int xcd = bid & 7, w = bid >> 3;                   // same-bh blocks share an XCD's L2
  int bh = xcd*8 + (w >> 3), qb = w & 7;
  int tid = threadIdx.x, lane = tid & 63, wv = tid >> 6;
  int l31 = lane & 31, hi = lane >> 5;
  const short* kp = k  + ((size_t)bh << 17);
  const short* vp = vT + ((size_t)bh << 17);
  int qrow = qb*256 + wv*32 + l31;
  const short* qp = q + ((size_t)bh << 17) + (size_t)qrow*64;
  s16x8 qf[4];                                       // B-frag: col=q(lane&31), k = d = 16*kk+8*hi+i
  #pragma unroll
  for (int kk=0;kk<4;kk++) qf[kk] = *(const s16x8*)(qp + kk*16 + hi*8);
  // ---- staging offsets (inverse-swizzled global source; LDS linear dest = tid*8 shorts/round) ----
  int kc0 = tid,      kr0 = kc0 >> 3;
  int kc1 = tid+512,  kr1 = kc1 >> 3;
  int koff0 = kr0*64 + ((kc0 ^ kr0) & 7)*8;
  int koff1 = kr1*64 + ((kc1 ^ kr1) & 7)*8;
  int vr0 = tid >> 4,       vcc0 = tid & 15;
  int vr1 = (tid+512) >> 4, vcc1 = (tid+512) & 15;
  int voff0 = vr0*2048 + ((vcc0 & 8) | ((vcc0 ^ vr0) & 7))*8;
  int voff1 = vr1*2048 + ((vcc1 & 8) | ((vcc1 ^ vr1) & 7))*8;

  f32x16 ot0 = z16(), ot1 = z16();                   // O^T: col=q, row = d
  float m = -1e30f, lr = 0.f;
  int rsw = (l31 & 7);                               // read-side chunk XOR

#define STAGE(nb, t) do { \
    gld16(kp + (size_t)(t)*8192 + koff0, &kbuf[nb][0]    + wv*512); \
    gld16(kp + (size_t)(t)*8192 + koff1, &kbuf[nb][4096] + wv*512); \
    gld16(vp + (size_t)(t)*128  + voff0, &vbuf[nb][0]    + wv*512); \
    gld16(vp + (size_t)(t)*128  + voff1, &vbuf[nb][4096] + wv*512); \
  } while(0)

  STAGE(0, 0);
  __syncthreads();

  for (int t = 0; t < 16; ++t){
    int cur = t & 1;
    if (t < 15) STAGE(cur^1, t+1);                   // drained by barrier at end of t
    #pragma unroll
    for (int h = 0; h < 2; ++h){
      const short* kb = &kbuf[cur][h*4096];
      const short* vb = &vbuf[cur][h*64];
      // ---- S^T = K . Q^T  (two 32x32 kv tiles, contraction d=64) ----
      f32x16 s0 = z16(), s1 = z16();
      __builtin_amdgcn_s_setprio(1);
      #pragma unroll
      for (int kk=0;kk<4;kk++){
        s16x8 kf0 = *(const s16x8*)(kb + l31*64       + (((kk*2 + hi) ^ rsw)*8));
        s0 = __builtin_amdgcn_mfma_f32_32x32x16_bf16(kf0, qf[kk], s0, 0, 0, 0);
        s16x8 kf1 = *(const s16x8*)(kb + (32+l31)*64  + (((kk*2 + hi) ^ rsw)*8));
        s1 = __builtin_amdgcn_mfma_f32_32x32x16_bf16(kf1, qf[kk], s1, 0, 0, 0);
      }
      __builtin_amdgcn_s_setprio(0);
      // ---- online softmax, lane-local per q-row (log2 domain) ----
      float tm[16];
      #pragma unroll
      for (int i=0;i<16;i++) tm[i] = fmaxf(s0[i], s1[i]);
      #pragma unroll
      for (int off=8; off>=1; off>>=1)
        #pragma unroll
        for (int i=0;i<off;i++) tm[i] = fmaxf(tm[i], tm[i+off]);
      float pmax = fmaxf(tm[0], __shfl_xor(tm[0], 32));
      if (!__all(pmax - m <= 8.0f)){                 // defer-max (T13)
        float mn = fmaxf(m, pmax);
        float al = fexp2(m - mn);
        m = mn; lr *= al;
        #pragma unroll
        for (int i=0;i<16;i++){ ot0[i] *= al; ot1[i] *= al; }
      }
      #pragma unroll
      for (int i=0;i<16;i++){ s0[i] = fexp2(s0[i]-m); s1[i] = fexp2(s1[i]-m); }
      float ra[16];
      #pragma unroll
      for (int i=0;i<16;i++) ra[i] = s0[i] + s1[i];
      #pragma unroll
      for (int off=8; off>=1; off>>=1)
        #pragma unroll
        for (int i=0;i<off;i++) ra[i] += ra[i+off];
      lr += ra[0] + __shfl_xor(ra[0], 32);
      // ---- P^T -> bf16 B-frags, O^T += V^T . P^T ----
      #pragma unroll
      for (int s4=0;s4<4;s4++){
        int base = (s4 & 1) * 8;
        int pkA0, pkA1, pkB0, pkB1;
        if (s4 < 2){
          pkA0 = cvtpk(s0[base],   s0[base+1]); pkA1 = cvtpk(s0[base+2], s0[base+3]);
          pkB0 = cvtpk(s0[base+4], s0[base+5]); pkB1 = cvtpk(s0[base+6], s0[base+7]);
        } else {
          pkA0 = cvtpk(s1[base],   s1[base+1]); pkA1 = cvtpk(s1[base+2], s1[base+3]);
          pkB0 = cvtpk(s1[base+4], s1[base+5]); pkB1 = cvtpk(s1[base+6], s1[base+7]);
        }
        int r0 = __shfl_xor(hi ? pkA0 : pkB0, 32);
        int r1 = __shfl_xor(hi ? pkA1 : pkB1, 32);
        union { int wq[4]; s16x8 v8; } u;
        u.wq[0] = hi ? r0   : pkA0;
        u.wq[1] = hi ? r1   : pkA1;
        u.wq[2] = hi ? pkB0 : r0;
        u.wq[3] = hi ? pkB1 : r1;
        __builtin_amdgcn_s_setprio(1);
        s16x8 vf0 = *(const s16x8*)(vb + l31*128      + (((s4*2 + hi) ^ rsw)*8));
        ot0 = __builtin_amdgcn_mfma_f32_32x32x16_bf16(vf0, u.v8, ot0, 0, 0, 0);
        s16x8 vf1 = *(const s16x8*)(vb + (32+l31)*128 + (((s4*2 + hi) ^ rsw)*8));
        ot1 = __builtin_amdgcn_mfma_f32_32x32x16_bf16(vf1, u.v8, ot1, 0, 0, 0);
        __builtin_amdgcn_s_setprio(0);
      }
    }
    __syncthreads();                                 // drains vmcnt (stage) + all waves done with cur
  }
#undef STAGE
  // ---- epilogue: out[b][s=q][h*64 + d], d = 8g + 4hi + j (+32 for db=1) ----
  float inv = 1.0f / lr;
  int b = bh >> 4, hh = bh & 15;
  float* orow = out + ((size_t)(b*Sd + qrow) << 10) + hh*64;
  #pragma unroll
  for (int g=0; g<4; ++g){
    f32x4 w0, w1;
    #pragma unroll
    for (int j=0;j<4;j++){ w0[j] = ot0[4*g+j]*inv; w1[j] = ot1[4*g+j]*inv; }
    *(f32x4*)(orow + g*8 + 4*hi)      = w0;
    *(f32x4*)(orow + 32 + g*8 + 4*hi) = w1;
  }
}

extern "C" void kernel_launch(void* const* d_in, const int* in_sizes, int n_in,
                              void* d_out, int out_size, void* d_ws, size_t ws_size,
                              hipStream_t stream){
  const float* hs = (const float*)d_in[0];
  const float* sp = (const float*)d_in[1];
  const float* lw = (const float*)d_in[2];
  const float* lb = (const float*)d_in[3];
  const float* wq = (const float*)d_in[4];
  const float* bq = (const float*)d_in[5];
  float* out = (float*)d_out;
  char* ws = (char*)d_ws;
  short* h   = (short*)(ws);
  short* wT  = (short*)(ws + 16777216);
  short* qb_ = (short*)(ws + 23068672);
  short* kb_ = (short*)(ws + 23068672 + 16777216);
  short* vTb = (short*)(ws + 23068672 + 33554432);   // [bh][D][S], written by GEMM epilogue

  hipLaunchKernelGGL(ln_kernel,    dim3(8192),    dim3(256),   0, stream, hs, lw, lb, h);
  hipLaunchKernelGGL(castw_kernel, dim3(96,32),   dim3(32,8),  0, stream, wq, wT);
  hipLaunchKernelGGL(gemm_kernel,  dim3(1536),    dim3(256),   0, stream, h, wT, bq, sp, qb_, kb_, vTb);
  hipLaunchKernelGGL(attn_kernel,  dim3(512),     dim3(512),   0, stream, qb_, kb_, vTb, out);
}